// Round 3
// baseline (694.562 us; speedup 1.0000x reference)
//
#include <hip/hip_runtime.h>
#include <hip/hip_bf16.h>
#include <cstdint>
#include <cstddef>

// Problem constants (B,S,D,H fixed by the reference)
#define Bc 4
#define Sc 2048
#define Dc 1024
#define Hc 16
// HD = 64

typedef __bf16 bf16;
typedef bf16  bf16x8 __attribute__((ext_vector_type(8)));
typedef float f32x4  __attribute__((ext_vector_type(4)));

// ---- 16-element row loaders: global (fp32 or bf16) -> two bf16x8 ----------
__device__ __forceinline__ void load16(const float* __restrict__ g,
                                       bf16x8& lo, bf16x8& hi) {
    const f32x4 a0 = *(const f32x4*)(g);
    const f32x4 a1 = *(const f32x4*)(g + 4);
    const f32x4 a2 = *(const f32x4*)(g + 8);
    const f32x4 a3 = *(const f32x4*)(g + 12);
#pragma unroll
    for (int j = 0; j < 4; j++) {
        lo[j]     = (bf16)a0[j];
        lo[j + 4] = (bf16)a1[j];
        hi[j]     = (bf16)a2[j];
        hi[j + 4] = (bf16)a3[j];
    }
}
__device__ __forceinline__ void load16(const bf16* __restrict__ g,
                                       bf16x8& lo, bf16x8& hi) {
    lo = *(const bf16x8*)(g);
    hi = *(const bf16x8*)(g + 8);
}

// ---- relu store: fp32 or bf16 destination ---------------------------------
__device__ __forceinline__ void store_relu(float* p, float v) { *p = fmaxf(v, 0.0f); }
__device__ __forceinline__ void store_relu(bf16*  p, float v) { *p = (bf16)fmaxf(v, 0.0f); }

// ---------------------------------------------------------------------------
// GEMM: C[M,N] = relu(A[M,K] @ W[N,K]^T + bias[N]).
// A: fp32 or bf16 (template), W/bias: fp32, C: fp32 or bf16 (template).
// Internal compute: bf16 MFMA with fp32 accumulation.
// 128x128 tile, BK=32, 256 threads (4 waves, each a 64x64 quadrant).
// ---------------------------------------------------------------------------
#define BM 128
#define BN 128
#define BK 32

template <typename TA, typename TC>
__global__ __launch_bounds__(256)
void gemm_bt_relu(const TA* __restrict__ A, const float* __restrict__ W,
                  const float* __restrict__ bias, TC* __restrict__ C,
                  int M, int N, int K) {
    __shared__ __align__(16) bf16 lA[BM * BK];
    __shared__ __align__(16) bf16 lB[BN * BK];

    const int t    = threadIdx.x;
    const int lane = t & 63;
    const int wave = t >> 6;
    const int l15  = lane & 15;
    const int quad = lane >> 4;

    const int m0 = blockIdx.x * BM;
    const int n0 = blockIdx.y * BN;
    const int wm = (wave >> 1) * 64;   // wave's 64x64 block within the tile
    const int wn = (wave & 1) * 64;

    f32x4 acc[4][4] = {};

    // staging: thread t covers 16 elems: row fr, cols [fc, fc+16)
    const int fr = t >> 1;             // 0..127
    const int fc = (t & 1) * 16;       // 0 or 16
    const TA*    gA = A + (size_t)(m0 + fr) * K + fc;
    const float* gW = W + (size_t)(n0 + fr) * K + fc;
    bf16* lA0 = lA + fr * BK + fc;
    bf16* lB0 = lB + fr * BK + fc;

    for (int k0 = 0; k0 < K; k0 += BK) {
        bf16x8 alo, ahi, wlo, whi;
        load16(gA, alo, ahi);
        load16(gW, wlo, whi);
        gA += BK; gW += BK;
        __syncthreads();               // previous tile fully consumed
        *(bf16x8*)(lA0)     = alo;
        *(bf16x8*)(lA0 + 8) = ahi;
        *(bf16x8*)(lB0)     = wlo;
        *(bf16x8*)(lB0 + 8) = whi;
        __syncthreads();               // tiles published

        bf16x8 af[4], bfr[4];
#pragma unroll
        for (int mt = 0; mt < 4; mt++)
            af[mt] = *(const bf16x8*)(lA + (wm + mt * 16 + l15) * BK + quad * 8);
#pragma unroll
        for (int nt = 0; nt < 4; nt++)
            bfr[nt] = *(const bf16x8*)(lB + (wn + nt * 16 + l15) * BK + quad * 8);
#pragma unroll
        for (int mt = 0; mt < 4; mt++)
#pragma unroll
            for (int nt = 0; nt < 4; nt++)
                acc[mt][nt] = __builtin_amdgcn_mfma_f32_16x16x32_bf16(
                    af[mt], bfr[nt], acc[mt][nt], 0, 0, 0);
    }

    // epilogue: C/D layout col = lane&15, row = quad*4 + i
#pragma unroll
    for (int nt = 0; nt < 4; nt++) {
        const int col = n0 + wn + nt * 16 + l15;
        const float bv = bias[col];
#pragma unroll
        for (int mt = 0; mt < 4; mt++) {
            const int rowb = m0 + wm + mt * 16 + quad * 4;
#pragma unroll
            for (int i = 0; i < 4; i++)
                store_relu(&C[(size_t)(rowb + i) * N + col], acc[mt][nt][i] + bv);
        }
    }
}

// ---------------------------------------------------------------------------
// Flash attention over bf16 intermediates. One block per (b, h, 64-row
// Q tile). 4 waves; wave w owns q rows [w*16, w*16+16). K/V tiles of 64 keys
// staged in LDS; online softmax; fp32 state.
// ---------------------------------------------------------------------------
__global__ __launch_bounds__(256)
void attn_flash(const bf16* __restrict__ Qh, const bf16* __restrict__ Kh,
                const bf16* __restrict__ Vh, bf16* __restrict__ Y) {
    __shared__ __align__(16) bf16 Kl[64 * 64];      // [key][hd]
    __shared__ __align__(16) bf16 Vt[64 * 64];      // [hd][key] (transposed)
    __shared__ __align__(16) bf16 Pl[4][16 * 64];   // per-wave P round-trip

    const int t    = threadIdx.x;
    const int lane = t & 63;
    const int wave = t >> 6;
    const int l15  = lane & 15;
    const int quad = lane >> 4;

    const int qt = blockIdx.x;          // 0..31
    const int bh = blockIdx.y;          // 0..63
    const int b  = bh >> 4;
    const int h  = bh & 15;
    const int q0 = qt * 64;
    const size_t rowbase = (size_t)b * Sc;

    // Q fragments for this wave's 16 q-rows (A-operand layout)
    const bf16* qp = Qh + (rowbase + q0 + wave * 16 + l15) * (size_t)Dc + h * 64;
    const bf16x8 qf0 = *(const bf16x8*)(qp + quad * 8);
    const bf16x8 qf1 = *(const bf16x8*)(qp + 32 + quad * 8);

    float mi[4], li[4];
    f32x4 yacc[4];
#pragma unroll
    for (int i = 0; i < 4; i++) { mi[i] = -1e30f; li[i] = 0.0f; }
#pragma unroll
    for (int nt = 0; nt < 4; nt++) yacc[nt] = (f32x4){0.f, 0.f, 0.f, 0.f};

    const int fr = (t * 8) >> 6;        // 0..31
    const int fc = (t * 8) & 63;        // 0,8,...,56

    for (int kt = 0; kt < Sc / 64; kt++) {
        const int kb = kt * 64;
        // ---- stage K (as-is) and V (transposed) ----
#pragma unroll
        for (int half = 0; half < 2; half++) {
            const int r = fr + half * 32;
            const bf16* kp = Kh + (rowbase + kb + r) * (size_t)Dc + h * 64 + fc;
            const bf16* vp = Vh + (rowbase + kb + r) * (size_t)Dc + h * 64 + fc;
            *(bf16x8*)(Kl + r * 64 + fc) = *(const bf16x8*)kp;
            const bf16x8 vv = *(const bf16x8*)vp;
#pragma unroll
            for (int j = 0; j < 8; j++) Vt[(fc + j) * 64 + r] = vv[j];
        }
        __syncthreads();

        // ---- scores: S = Q K^T * (1/8) ----
        f32x4 s[4];
#pragma unroll
        for (int nt = 0; nt < 4; nt++) {
            s[nt] = (f32x4){0.f, 0.f, 0.f, 0.f};
            const bf16x8 k0 = *(const bf16x8*)(Kl + (nt * 16 + l15) * 64 + quad * 8);
            const bf16x8 k1 = *(const bf16x8*)(Kl + (nt * 16 + l15) * 64 + 32 + quad * 8);
            s[nt] = __builtin_amdgcn_mfma_f32_16x16x32_bf16(qf0, k0, s[nt], 0, 0, 0);
            s[nt] = __builtin_amdgcn_mfma_f32_16x16x32_bf16(qf1, k1, s[nt], 0, 0, 0);
            s[nt] *= 0.125f;
        }

        // ---- online softmax (row quad*4+i; reduce across the 16 l15 lanes) ----
#pragma unroll
        for (int i = 0; i < 4; i++) {
            float mx = fmaxf(fmaxf(s[0][i], s[1][i]), fmaxf(s[2][i], s[3][i]));
            mx = fmaxf(mx, __shfl_xor(mx, 1));
            mx = fmaxf(mx, __shfl_xor(mx, 2));
            mx = fmaxf(mx, __shfl_xor(mx, 4));
            mx = fmaxf(mx, __shfl_xor(mx, 8));
            const float mnew  = fmaxf(mi[i], mx);
            const float alpha = __expf(mi[i] - mnew);
            float ps = 0.f;
#pragma unroll
            for (int nt = 0; nt < 4; nt++) {
                const float p = __expf(s[nt][i] - mnew);
                s[nt][i] = p;
                ps += p;
            }
            ps += __shfl_xor(ps, 1);
            ps += __shfl_xor(ps, 2);
            ps += __shfl_xor(ps, 4);
            ps += __shfl_xor(ps, 8);
            li[i] = li[i] * alpha + ps;
            mi[i] = mnew;
#pragma unroll
            for (int nt = 0; nt < 4; nt++) yacc[nt][i] *= alpha;
        }

        // ---- P: C-layout -> A-operand layout via per-wave LDS ----
#pragma unroll
        for (int nt = 0; nt < 4; nt++)
#pragma unroll
            for (int i = 0; i < 4; i++)
                Pl[wave][(quad * 4 + i) * 64 + nt * 16 + l15] = (bf16)s[nt][i];
        const bf16x8 pa0 = *(const bf16x8*)(&Pl[wave][l15 * 64 + quad * 8]);
        const bf16x8 pa1 = *(const bf16x8*)(&Pl[wave][l15 * 64 + 32 + quad * 8]);

        // ---- PV: Y += P @ V  (B operand from transposed V) ----
#pragma unroll
        for (int nt = 0; nt < 4; nt++) {
            const bf16x8 v0 = *(const bf16x8*)(Vt + (nt * 16 + l15) * 64 + quad * 8);
            const bf16x8 v1 = *(const bf16x8*)(Vt + (nt * 16 + l15) * 64 + 32 + quad * 8);
            yacc[nt] = __builtin_amdgcn_mfma_f32_16x16x32_bf16(pa0, v0, yacc[nt], 0, 0, 0);
            yacc[nt] = __builtin_amdgcn_mfma_f32_16x16x32_bf16(pa1, v1, yacc[nt], 0, 0, 0);
        }
        __syncthreads();   // done with Kl/Vt; safe to restage
    }

    // ---- normalize and store Y (bf16, [B,S,D] with head offset) ----
#pragma unroll
    for (int i = 0; i < 4; i++) {
        const float inv = 1.0f / li[i];
        const int row = q0 + wave * 16 + quad * 4 + i;
        bf16* yp = Y + (rowbase + row) * (size_t)Dc + h * 64;
#pragma unroll
        for (int nt = 0; nt < 4; nt++)
            yp[nt * 16 + l15] = (bf16)(yacc[nt][i] * inv);
    }
}

// ---------------------------------------------------------------------------
extern "C" void kernel_launch(void* const* d_in, const int* in_sizes, int n_in,
                              void* d_out, int out_size, void* d_ws, size_t ws_size,
                              hipStream_t stream) {
    // ALL inputs are fp32 (per the reference); output is fp32.
    const float* q  = (const float*)d_in[0];
    const float* k  = (const float*)d_in[1];
    const float* v  = (const float*)d_in[2];
    const float* Wq = (const float*)d_in[3];
    const float* bq = (const float*)d_in[4];
    const float* Wk = (const float*)d_in[5];
    const float* bk = (const float*)d_in[6];
    const float* Wv = (const float*)d_in[7];
    const float* bv = (const float*)d_in[8];
    const float* Wo = (const float*)d_in[9];
    const float* bo = (const float*)d_in[10];
    float* out = (float*)d_out;

    const int M = Bc * Sc;   // 8192
    const int N = Dc;        // 1024
    const int K = Dc;        // 1024

    // bf16 intermediates. Qh|Kh exactly fill d_out (2 * E * 2B = out fp32
    // bytes); they are dead before the final GEMM overwrites d_out with fp32
    // (stream ordering). Vh|Yw live in d_ws (33.5 MB).
    const size_t E = (size_t)Bc * Sc * Dc;
    bf16* Qh = (bf16*)d_out;
    bf16* Kh = Qh + E;
    bf16* Vh = (bf16*)d_ws;
    bf16* Yw = Vh + E;

    dim3 gg(M / BM, N / BN);   // 64 x 8
    gemm_bt_relu<float, bf16><<<gg, 256, 0, stream>>>(q, Wq, bq, Qh, M, N, K);
    gemm_bt_relu<float, bf16><<<gg, 256, 0, stream>>>(k, Wk, bk, Kh, M, N, K);
    gemm_bt_relu<float, bf16><<<gg, 256, 0, stream>>>(v, Wv, bv, Vh, M, N, K);

    dim3 ga(Sc / 64, Bc * Hc); // 32 x 64
    attn_flash<<<ga, 256, 0, stream>>>(Qh, Kh, Vh, Yw);

    gemm_bt_relu<bf16, float><<<gg, 256, 0, stream>>>(Yw, Wo, bo, out, M, N, K);
}

// Round 4
// 548.919 us; speedup vs baseline: 1.2653x; 1.2653x over previous
//
#include <hip/hip_runtime.h>
#include <hip/hip_bf16.h>
#include <cstdint>
#include <cstddef>

// Problem constants (B,S,D,H fixed by the reference)
#define Bc 4
#define Sc 2048
#define Dc 1024
#define Hc 16
// HD = 64

typedef __bf16 bf16;
typedef bf16  bf16x8 __attribute__((ext_vector_type(8)));
typedef float f32x4  __attribute__((ext_vector_type(4)));

__device__ __forceinline__ void load_lds16(const bf16* g, bf16* l) {
    __builtin_amdgcn_global_load_lds((const __attribute__((address_space(1))) void*)g,
                                     (__attribute__((address_space(3))) void*)l,
                                     16, 0, 0);
}

// 16 fp32 -> two bf16x8
__device__ __forceinline__ void cvt16(const float* __restrict__ g,
                                      bf16x8& lo, bf16x8& hi) {
    const f32x4 a0 = *(const f32x4*)(g);
    const f32x4 a1 = *(const f32x4*)(g + 4);
    const f32x4 a2 = *(const f32x4*)(g + 8);
    const f32x4 a3 = *(const f32x4*)(g + 12);
#pragma unroll
    for (int j = 0; j < 4; j++) {
        lo[j]     = (bf16)a0[j];
        lo[j + 4] = (bf16)a1[j];
        hi[j]     = (bf16)a2[j];
        hi[j + 4] = (bf16)a3[j];
    }
}

__device__ __forceinline__ void store_relu(float* p, float v) { *p = fmaxf(v, 0.0f); }
__device__ __forceinline__ void store_relu(bf16*  p, float v) { *p = (bf16)fmaxf(v, 0.0f); }

// ---------------------------------------------------------------------------
// fp32 -> bf16 conversion (vectorized, 16 elems/thread)
// ---------------------------------------------------------------------------
__global__ __launch_bounds__(256)
void cvt_f32_bf16(const float* __restrict__ src, bf16* __restrict__ dst, int n16) {
    const int idx = blockIdx.x * 256 + threadIdx.x;
    if (idx >= n16) return;
    bf16x8 lo, hi;
    cvt16(src + (size_t)idx * 16, lo, hi);
    *(bf16x8*)(dst + (size_t)idx * 16)     = lo;
    *(bf16x8*)(dst + (size_t)idx * 16 + 8) = hi;
}

// ---------------------------------------------------------------------------
// GEMM: C = relu(A[M,K](bf16) @ W[N,K]^T(fp32, converted in-kernel) + bias).
// m97 structure: 128x128 tile, BK=32, A staged via global_load_lds width-16.
// TR=true: output written transposed per head for the V projection:
//   Vt_g[((b*16+h)*64 + hd) * Sc + s]
// ---------------------------------------------------------------------------
#define BM 128
#define BN 128
#define BK 32

template <typename TC, bool TR>
__global__ __launch_bounds__(256)
void gemm_hyb(const bf16* __restrict__ A, const float* __restrict__ W,
              const float* __restrict__ bias, TC* __restrict__ C,
              int M, int N, int K) {
    __shared__ __align__(16) bf16 lA[BM * BK];
    __shared__ __align__(16) bf16 lB[BN * BK];

    const int t    = threadIdx.x;
    const int lane = t & 63;
    const int wave = t >> 6;
    const int l15  = lane & 15;
    const int quad = lane >> 4;

    const int m0 = blockIdx.x * BM;
    const int n0 = blockIdx.y * BN;
    const int wm = (wave >> 1) * 64;
    const int wn = (wave & 1) * 64;

    f32x4 acc[4][4] = {};

    // A staging (global_load_lds): thread t -> flat elems [t*8, t*8+8) + 2048
    const int fr = t >> 2;             // row 0..63 (and +64)
    const int fc = (t & 3) * 8;        // col 0,8,16,24
    const bf16* gA = A + (size_t)(m0 + fr) * K + fc;
    bf16* lA0 = lA + t * 8;            // wave-uniform base + lane*16B

    // W staging (fp32 -> bf16 in regs): 16 elems/thread
    const int wr = t >> 1;             // row 0..127
    const int wc = (t & 1) * 16;       // col 0 or 16
    const float* gW = W + (size_t)(n0 + wr) * K + wc;
    bf16* lB0 = lB + wr * BK + wc;

    for (int k0 = 0; k0 < K; k0 += BK) {
        bf16x8 wlo, whi;
        cvt16(gW, wlo, whi);           // global loads issued before barrier
        __syncthreads();               // all waves done reading prev tiles
        load_lds16(gA, lA0);
        load_lds16(gA + (size_t)64 * K, lA0 + 2048);
        *(bf16x8*)(lB0)     = wlo;
        *(bf16x8*)(lB0 + 8) = whi;
        gA += BK; gW += BK;
        __syncthreads();               // drains vmcnt (lds-DMA) + lgkm

        bf16x8 af[4], bfr[4];
#pragma unroll
        for (int mt = 0; mt < 4; mt++)
            af[mt] = *(const bf16x8*)(lA + (wm + mt * 16 + l15) * BK + quad * 8);
#pragma unroll
        for (int nt = 0; nt < 4; nt++)
            bfr[nt] = *(const bf16x8*)(lB + (wn + nt * 16 + l15) * BK + quad * 8);
#pragma unroll
        for (int mt = 0; mt < 4; mt++)
#pragma unroll
            for (int nt = 0; nt < 4; nt++)
                acc[mt][nt] = __builtin_amdgcn_mfma_f32_16x16x32_bf16(
                    af[mt], bfr[nt], acc[mt][nt], 0, 0, 0);
    }

    if constexpr (!TR) {
        // C/D layout: col = lane&15, row = quad*4 + i
#pragma unroll
        for (int nt = 0; nt < 4; nt++) {
            const int col = n0 + wn + nt * 16 + l15;
            const float bv = bias[col];
#pragma unroll
            for (int mt = 0; mt < 4; mt++) {
                const int rowb = m0 + wm + mt * 16 + quad * 4;
#pragma unroll
                for (int i = 0; i < 4; i++)
                    store_relu(&C[(size_t)(rowb + i) * N + col], acc[mt][nt][i] + bv);
            }
        }
    } else {
        // Transposed per-head output via LDS transpose (once per kernel).
        __shared__ __align__(16) bf16 tr[4][64][72];
#pragma unroll
        for (int nt = 0; nt < 4; nt++) {
            const int col = n0 + wn + nt * 16 + l15;
            const float bv = bias[col];
#pragma unroll
            for (int mt = 0; mt < 4; mt++)
#pragma unroll
                for (int i = 0; i < 4; i++)
                    tr[wave][nt * 16 + l15][mt * 16 + quad * 4 + i] =
                        (bf16)fmaxf(acc[mt][nt][i] + bv, 0.0f);
        }
        __syncthreads();   // publish (also orders same-wave b16->b128)
        const int r2 = lane >> 3;          // 0..7
        const int c8 = (lane & 7) * 8;     // 0..56
#pragma unroll
        for (int rr = 0; rr < 8; rr++) {
            const int rt = rr * 8 + r2;                  // quadrant col (hd dim)
            const bf16x8 vv = *(const bf16x8*)&tr[wave][rt][c8];
            const int cg = n0 + wn + rt;                 // global col
            const int h  = cg >> 6, hd = cg & 63;
            const int mg = m0 + wm + c8;                 // global row base
            const int b  = mg >> 11, s = mg & (Sc - 1);
            bf16* dst = (bf16*)C + ((size_t)(b * Hc + h) * 64 + hd) * Sc + s;
            *(bf16x8*)dst = vv;
        }
    }
}

// ---------------------------------------------------------------------------
// Flash attention. V comes in pre-transposed per head: Vt_g[b][h][hd][s].
// All LDS strides padded to 72 elems (144 B) to break bank aliasing.
// ---------------------------------------------------------------------------
__global__ __launch_bounds__(256)
void attn_flash(const bf16* __restrict__ Qh, const bf16* __restrict__ Kh,
                const bf16* __restrict__ Vt_g, bf16* __restrict__ Y) {
    __shared__ __align__(16) bf16 Kl[64][72];      // [key][hd]
    __shared__ __align__(16) bf16 Vl[64][72];      // [hd][key]
    __shared__ __align__(16) bf16 Pl[4][16][72];   // per-wave P round-trip

    const int t    = threadIdx.x;
    const int lane = t & 63;
    const int wave = t >> 6;
    const int l15  = lane & 15;
    const int quad = lane >> 4;

    const int qt = blockIdx.x;          // 0..31
    const int bh = blockIdx.y;          // 0..63
    const int b  = bh >> 4;
    const int h  = bh & 15;
    const int q0 = qt * 64;
    const size_t rowbase = (size_t)b * Sc;
    const size_t vhead   = (size_t)(b * Hc + h) * 64;  // row base into Vt_g

    // Q fragments (A-operand layout), direct from global
    const bf16* qp = Qh + (rowbase + q0 + wave * 16 + l15) * (size_t)Dc + h * 64;
    const bf16x8 qf0 = *(const bf16x8*)(qp + quad * 8);
    const bf16x8 qf1 = *(const bf16x8*)(qp + 32 + quad * 8);

    float mi[4], li[4];
    f32x4 yacc[4];
#pragma unroll
    for (int i = 0; i < 4; i++) { mi[i] = -1e30f; li[i] = 0.0f; }
#pragma unroll
    for (int nt = 0; nt < 4; nt++) yacc[nt] = (f32x4){0.f, 0.f, 0.f, 0.f};

    // staging map: thread covers row sr, cols [sc, sc+16)
    const int sr = t >> 2;              // 0..63
    const int sc = (t & 3) * 16;        // 0,16,32,48

    for (int kt = 0; kt < Sc / 64; kt++) {
        const int kb = kt * 64;
        const bf16* kp = Kh + (rowbase + kb + sr) * (size_t)Dc + h * 64 + sc;
        const bf16* vp = Vt_g + (vhead + sr) * (size_t)Sc + kb + sc;
        const bf16x8 k0 = *(const bf16x8*)kp;
        const bf16x8 k1 = *(const bf16x8*)(kp + 8);
        const bf16x8 v0 = *(const bf16x8*)vp;
        const bf16x8 v1 = *(const bf16x8*)(vp + 8);
        __syncthreads();                // prev tile fully consumed
        *(bf16x8*)&Kl[sr][sc]     = k0;
        *(bf16x8*)&Kl[sr][sc + 8] = k1;
        *(bf16x8*)&Vl[sr][sc]     = v0;
        *(bf16x8*)&Vl[sr][sc + 8] = v1;
        __syncthreads();                // tiles published

        // ---- scores: S = Q K^T * (1/8) ----
        f32x4 s[4];
#pragma unroll
        for (int nt = 0; nt < 4; nt++) {
            s[nt] = (f32x4){0.f, 0.f, 0.f, 0.f};
            const bf16x8 kk0 = *(const bf16x8*)&Kl[nt * 16 + l15][quad * 8];
            const bf16x8 kk1 = *(const bf16x8*)&Kl[nt * 16 + l15][32 + quad * 8];
            s[nt] = __builtin_amdgcn_mfma_f32_16x16x32_bf16(qf0, kk0, s[nt], 0, 0, 0);
            s[nt] = __builtin_amdgcn_mfma_f32_16x16x32_bf16(qf1, kk1, s[nt], 0, 0, 0);
            s[nt] *= 0.125f;
        }

        // ---- online softmax (row quad*4+i; reduce across 16 l15 lanes) ----
#pragma unroll
        for (int i = 0; i < 4; i++) {
            float mx = fmaxf(fmaxf(s[0][i], s[1][i]), fmaxf(s[2][i], s[3][i]));
            mx = fmaxf(mx, __shfl_xor(mx, 1));
            mx = fmaxf(mx, __shfl_xor(mx, 2));
            mx = fmaxf(mx, __shfl_xor(mx, 4));
            mx = fmaxf(mx, __shfl_xor(mx, 8));
            const float mnew  = fmaxf(mi[i], mx);
            const float alpha = __expf(mi[i] - mnew);
            float ps = 0.f;
#pragma unroll
            for (int nt = 0; nt < 4; nt++) {
                const float p = __expf(s[nt][i] - mnew);
                s[nt][i] = p;
                ps += p;
            }
            ps += __shfl_xor(ps, 1);
            ps += __shfl_xor(ps, 2);
            ps += __shfl_xor(ps, 4);
            ps += __shfl_xor(ps, 8);
            li[i] = li[i] * alpha + ps;
            mi[i] = mnew;
#pragma unroll
            for (int nt = 0; nt < 4; nt++) yacc[nt][i] *= alpha;
        }

        // ---- P: C-layout -> A-operand layout via per-wave LDS ----
#pragma unroll
        for (int nt = 0; nt < 4; nt++)
#pragma unroll
            for (int i = 0; i < 4; i++)
                Pl[wave][quad * 4 + i][nt * 16 + l15] = (bf16)s[nt][i];
        const bf16x8 pa0 = *(const bf16x8*)&Pl[wave][l15][quad * 8];
        const bf16x8 pa1 = *(const bf16x8*)&Pl[wave][l15][32 + quad * 8];

        // ---- PV: Y += P @ V  (B operand = Vl[hd][key]) ----
#pragma unroll
        for (int nt = 0; nt < 4; nt++) {
            const bf16x8 vv0 = *(const bf16x8*)&Vl[nt * 16 + l15][quad * 8];
            const bf16x8 vv1 = *(const bf16x8*)&Vl[nt * 16 + l15][32 + quad * 8];
            yacc[nt] = __builtin_amdgcn_mfma_f32_16x16x32_bf16(pa0, vv0, yacc[nt], 0, 0, 0);
            yacc[nt] = __builtin_amdgcn_mfma_f32_16x16x32_bf16(pa1, vv1, yacc[nt], 0, 0, 0);
        }
        __syncthreads();   // done with Kl/Vl; safe to restage
    }

    // ---- normalize and store Y (bf16, [B,S,D] with head offset) ----
#pragma unroll
    for (int i = 0; i < 4; i++) {
        const float inv = 1.0f / li[i];
        const int row = q0 + wave * 16 + quad * 4 + i;
        bf16* yp = Y + (rowbase + row) * (size_t)Dc + h * 64;
#pragma unroll
        for (int nt = 0; nt < 4; nt++)
            yp[nt * 16 + l15] = (bf16)(yacc[nt][i] * inv);
    }
}

// ---------------------------------------------------------------------------
extern "C" void kernel_launch(void* const* d_in, const int* in_sizes, int n_in,
                              void* d_out, int out_size, void* d_ws, size_t ws_size,
                              hipStream_t stream) {
    const float* q  = (const float*)d_in[0];
    const float* k  = (const float*)d_in[1];
    const float* v  = (const float*)d_in[2];
    const float* Wq = (const float*)d_in[3];
    const float* bq = (const float*)d_in[4];
    const float* Wk = (const float*)d_in[5];
    const float* bk = (const float*)d_in[6];
    const float* Wv = (const float*)d_in[7];
    const float* bv = (const float*)d_in[8];
    const float* Wo = (const float*)d_in[9];
    const float* bo = (const float*)d_in[10];
    float* out = (float*)d_out;

    const int M = Bc * Sc;   // 8192
    const int N = Dc;        // 1024
    const int K = Dc;        // 1024
    const size_t E = (size_t)Bc * Sc * Dc;   // 8388608

    // d_out: Qh | Kh (bf16, exactly out bytes; dead before final GEMM writes).
    // d_ws:  tmpA | Vt_g (bf16, 33.55 MB total — proven footprint).
    // tmpA holds qb/kb/vb sequentially, then the attention output Yw.
    bf16* Qh   = (bf16*)d_out;
    bf16* Kh   = Qh + E;
    bf16* tmpA = (bf16*)d_ws;
    bf16* VtG  = tmpA + E;

    const int n16 = (int)(E / 16);           // 524288
    dim3 gc(n16 / 256);                      // 2048 blocks
    dim3 gg(M / BM, N / BN);                 // 64 x 8
    dim3 ga(Sc / 64, Bc * Hc);               // 32 x 64

    cvt_f32_bf16<<<gc, 256, 0, stream>>>(q, tmpA, n16);
    gemm_hyb<bf16, false><<<gg, 256, 0, stream>>>(tmpA, Wq, bq, Qh, M, N, K);

    cvt_f32_bf16<<<gc, 256, 0, stream>>>(k, tmpA, n16);
    gemm_hyb<bf16, false><<<gg, 256, 0, stream>>>(tmpA, Wk, bk, Kh, M, N, K);

    cvt_f32_bf16<<<gc, 256, 0, stream>>>(v, tmpA, n16);
    gemm_hyb<bf16, true><<<gg, 256, 0, stream>>>(tmpA, Wv, bv, VtG, M, N, K);

    attn_flash<<<ga, 256, 0, stream>>>(Qh, Kh, VtG, tmpA);

    gemm_hyb<float, false><<<gg, 256, 0, stream>>>(tmpA, Wo, bo, out, M, N, K);
}

// Round 5
// 441.851 us; speedup vs baseline: 1.5719x; 1.2423x over previous
//
#include <hip/hip_runtime.h>
#include <hip/hip_bf16.h>
#include <cstdint>
#include <cstddef>

// Problem constants (B,S,D,H fixed by the reference)
#define Bc 4
#define Sc 2048
#define Dc 1024
#define Hc 16
// HD = 64

typedef __bf16 bf16;
typedef bf16  bf16x8 __attribute__((ext_vector_type(8)));
typedef float f32x4  __attribute__((ext_vector_type(4)));

__device__ __forceinline__ void load_lds16(const bf16* g, bf16* l) {
    __builtin_amdgcn_global_load_lds((const __attribute__((address_space(1))) void*)g,
                                     (__attribute__((address_space(3))) void*)l,
                                     16, 0, 0);
}

// 16 fp32 -> two bf16x8
__device__ __forceinline__ void cvt16(const float* __restrict__ g,
                                      bf16x8& lo, bf16x8& hi) {
    const f32x4 a0 = *(const f32x4*)(g);
    const f32x4 a1 = *(const f32x4*)(g + 4);
    const f32x4 a2 = *(const f32x4*)(g + 8);
    const f32x4 a3 = *(const f32x4*)(g + 12);
#pragma unroll
    for (int j = 0; j < 4; j++) {
        lo[j]     = (bf16)a0[j];
        lo[j + 4] = (bf16)a1[j];
        hi[j]     = (bf16)a2[j];
        hi[j + 4] = (bf16)a3[j];
    }
}

__device__ __forceinline__ void store_relu(float* p, float v) { *p = fmaxf(v, 0.0f); }
__device__ __forceinline__ void store_relu(bf16*  p, float v) { *p = (bf16)fmaxf(v, 0.0f); }

// ---------------------------------------------------------------------------
// fp32 -> bf16 conversion (16 elems/thread)
// ---------------------------------------------------------------------------
__global__ __launch_bounds__(256)
void cvt_f32_bf16(const float* __restrict__ src, bf16* __restrict__ dst, int n16) {
    const int idx = blockIdx.x * 256 + threadIdx.x;
    if (idx >= n16) return;
    bf16x8 lo, hi;
    cvt16(src + (size_t)idx * 16, lo, hi);
    *(bf16x8*)(dst + (size_t)idx * 16)     = lo;
    *(bf16x8*)(dst + (size_t)idx * 16 + 8) = hi;
}

// ---------------------------------------------------------------------------
// GEMM: C = relu(A[M,K] @ W[N,K]^T + bias), A and W bf16, pure m97 structure:
// 128x128 tile, BK=32, both operands staged via global_load_lds width-16.
// TR=true: V-projection epilogue writes per-head transposed:
//   Vt_g[((b*16+h)*64 + hd) * Sc + s]
// ---------------------------------------------------------------------------
#define BM 128
#define BN 128
#define BK 32

template <typename TC, bool TR>
__global__ __launch_bounds__(256)
void gemm_bb(const bf16* __restrict__ A, const bf16* __restrict__ W,
             const float* __restrict__ bias, TC* __restrict__ C,
             int M, int N, int K) {
    __shared__ __align__(16) bf16 lA[BM * BK];
    __shared__ __align__(16) bf16 lB[BN * BK];

    const int t    = threadIdx.x;
    const int lane = t & 63;
    const int wave = t >> 6;
    const int l15  = lane & 15;
    const int quad = lane >> 4;

    const int m0 = blockIdx.x * BM;
    const int n0 = blockIdx.y * BN;
    const int wm = (wave >> 1) * 64;
    const int wn = (wave & 1) * 64;

    f32x4 acc[4][4] = {};

    // staging map: thread t -> tile-flat elems [t*8, t*8+8) (row t>>2, col (t&3)*8)
    const int fr = t >> 2;
    const int fc = (t & 3) * 8;
    const bf16* gA = A + (size_t)(m0 + fr) * K + fc;
    const bf16* gW = W + (size_t)(n0 + fr) * K + fc;
    bf16* lA0 = lA + t * 8;            // wave-uniform base + lane*16B
    bf16* lB0 = lB + t * 8;

    for (int k0 = 0; k0 < K; k0 += BK) {
        __syncthreads();               // previous tiles fully consumed
        load_lds16(gA,                  lA0);
        load_lds16(gA + (size_t)64 * K, lA0 + 2048);
        load_lds16(gW,                  lB0);
        load_lds16(gW + (size_t)64 * K, lB0 + 2048);
        gA += BK; gW += BK;
        __syncthreads();               // drains vmcnt -> tiles published

        bf16x8 af[4], bfr[4];
#pragma unroll
        for (int mt = 0; mt < 4; mt++)
            af[mt] = *(const bf16x8*)(lA + (wm + mt * 16 + l15) * BK + quad * 8);
#pragma unroll
        for (int nt = 0; nt < 4; nt++)
            bfr[nt] = *(const bf16x8*)(lB + (wn + nt * 16 + l15) * BK + quad * 8);
#pragma unroll
        for (int mt = 0; mt < 4; mt++)
#pragma unroll
            for (int nt = 0; nt < 4; nt++)
                acc[mt][nt] = __builtin_amdgcn_mfma_f32_16x16x32_bf16(
                    af[mt], bfr[nt], acc[mt][nt], 0, 0, 0);
    }

    if constexpr (!TR) {
        // C/D layout: col = lane&15, row = quad*4 + i
#pragma unroll
        for (int nt = 0; nt < 4; nt++) {
            const int col = n0 + wn + nt * 16 + l15;
            const float bv = bias[col];
#pragma unroll
            for (int mt = 0; mt < 4; mt++) {
                const int rowb = m0 + wm + mt * 16 + quad * 4;
#pragma unroll
                for (int i = 0; i < 4; i++)
                    store_relu(&C[(size_t)(rowb + i) * N + col], acc[mt][nt][i] + bv);
            }
        }
    } else {
        // Transposed per-head output via LDS transpose (once per kernel).
        __shared__ __align__(16) bf16 tr[4][64][72];
#pragma unroll
        for (int nt = 0; nt < 4; nt++) {
            const int col = n0 + wn + nt * 16 + l15;
            const float bv = bias[col];
#pragma unroll
            for (int mt = 0; mt < 4; mt++)
#pragma unroll
                for (int i = 0; i < 4; i++)
                    tr[wave][nt * 16 + l15][mt * 16 + quad * 4 + i] =
                        (bf16)fmaxf(acc[mt][nt][i] + bv, 0.0f);
        }
        __syncthreads();
        const int r2 = lane >> 3;          // 0..7
        const int c8 = (lane & 7) * 8;     // 0..56
#pragma unroll
        for (int rr = 0; rr < 8; rr++) {
            const int rt = rr * 8 + r2;                  // quadrant col (hd dim)
            const bf16x8 vv = *(const bf16x8*)&tr[wave][rt][c8];
            const int cg = n0 + wn + rt;                 // global col
            const int h  = cg >> 6, hd = cg & 63;
            const int mg = m0 + wm + c8;                 // global row base
            const int b  = mg >> 11, s = mg & (Sc - 1);
            bf16* dst = (bf16*)C + ((size_t)(b * Hc + h) * 64 + hd) * Sc + s;
            *(bf16x8*)dst = vv;
        }
    }
}

// ---------------------------------------------------------------------------
// Flash attention, transposed-score form. S^T = K Q^T so softmax state is
// per-lane (query = l15); reductions = in-lane tree + 2 shuffles.
// 128 queries/block (4 waves x 2 Q-frags), 64-key tiles.
// V pre-transposed per head: Vt_g[b][h][hd][s]. O accumulated transposed.
// ---------------------------------------------------------------------------
__global__ __launch_bounds__(256)
void attn_flash(const bf16* __restrict__ Qh, const bf16* __restrict__ Kh,
                const bf16* __restrict__ Vt_g, bf16* __restrict__ Y) {
    __shared__ __align__(16) bf16 Kl[64][72];      // [key][hd]
    __shared__ __align__(16) bf16 Vl[64][72];      // [hd][key]
    __shared__ __align__(16) bf16 Pl[4][32][72];   // per-wave P^T rows=query

    const int t    = threadIdx.x;
    const int lane = t & 63;
    const int wave = t >> 6;
    const int l15  = lane & 15;
    const int quad = lane >> 4;

    const int qt = blockIdx.x;          // 0..15
    const int bh = blockIdx.y;          // 0..63
    const int b  = bh >> 4;
    const int h  = bh & 15;
    const int q0 = qt * 128;
    const size_t rowbase = (size_t)b * Sc;
    const size_t vhead   = (size_t)(b * Hc + h) * 64;

    // Q fragments as B-operand [n=query=l15][k=hd=quad*8+j], scaled by
    // 1/8 * log2(e) so scores are in the exp2 domain.
    const float qscale = 0.125f * 1.44269504f;
    bf16x8 qf[2][2];
#pragma unroll
    for (int qi = 0; qi < 2; qi++) {
        const bf16* qp = Qh + (rowbase + q0 + wave * 32 + qi * 16 + l15) * (size_t)Dc + h * 64;
#pragma unroll
        for (int ks = 0; ks < 2; ks++) {
            const bf16x8 raw = *(const bf16x8*)(qp + ks * 32 + quad * 8);
#pragma unroll
            for (int j = 0; j < 8; j++) qf[qi][ks][j] = (bf16)((float)raw[j] * qscale);
        }
    }

    float mrun[2] = {-1e30f, -1e30f};
    float lrun[2] = {0.0f, 0.0f};
    f32x4 yacc[2][4] = {};   // O^T: col=query=l15, row=hd=nt*16+quad*4+i

    // staging map: thread covers row sr, cols [sc, sc+16)
    const int sr = t >> 2;
    const int sc = (t & 3) * 16;

    for (int kt = 0; kt < Sc / 64; kt++) {
        const int kb = kt * 64;
        const bf16* kp = Kh + (rowbase + kb + sr) * (size_t)Dc + h * 64 + sc;
        const bf16* vp = Vt_g + (vhead + sr) * (size_t)Sc + kb + sc;
        const bf16x8 k0 = *(const bf16x8*)kp;
        const bf16x8 k1 = *(const bf16x8*)(kp + 8);
        const bf16x8 v0 = *(const bf16x8*)vp;
        const bf16x8 v1 = *(const bf16x8*)(vp + 8);
        __syncthreads();                // prev tile fully consumed
        *(bf16x8*)&Kl[sr][sc]     = k0;
        *(bf16x8*)&Kl[sr][sc + 8] = k1;
        *(bf16x8*)&Vl[sr][sc]     = v0;
        *(bf16x8*)&Vl[sr][sc + 8] = v1;
        __syncthreads();                // tiles published

        // ---- K fragments (A-operand [m=key][k=hd]), shared across qi ----
        bf16x8 kf[4][2];
#pragma unroll
        for (int mt = 0; mt < 4; mt++) {
            kf[mt][0] = *(const bf16x8*)&Kl[mt * 16 + l15][quad * 8];
            kf[mt][1] = *(const bf16x8*)&Kl[mt * 16 + l15][32 + quad * 8];
        }

        // ---- scores S^T: col=query=l15, row=key=mt*16+quad*4+i ----
        f32x4 s[2][4];
#pragma unroll
        for (int qi = 0; qi < 2; qi++)
#pragma unroll
            for (int mt = 0; mt < 4; mt++) {
                s[qi][mt] = (f32x4){0.f, 0.f, 0.f, 0.f};
                s[qi][mt] = __builtin_amdgcn_mfma_f32_16x16x32_bf16(
                    kf[mt][0], qf[qi][0], s[qi][mt], 0, 0, 0);
                s[qi][mt] = __builtin_amdgcn_mfma_f32_16x16x32_bf16(
                    kf[mt][1], qf[qi][1], s[qi][mt], 0, 0, 0);
            }

        // ---- online softmax, per query (= per lane), exp2 domain ----
#pragma unroll
        for (int qi = 0; qi < 2; qi++) {
            float mx = s[qi][0][0];
#pragma unroll
            for (int mt = 0; mt < 4; mt++)
#pragma unroll
                for (int i = 0; i < 4; i++) mx = fmaxf(mx, s[qi][mt][i]);
            mx = fmaxf(mx, __shfl_xor(mx, 16));
            mx = fmaxf(mx, __shfl_xor(mx, 32));
            const float mnew  = fmaxf(mrun[qi], mx);
            const float alpha = exp2f(mrun[qi] - mnew);
            float sum = 0.f;
#pragma unroll
            for (int mt = 0; mt < 4; mt++)
#pragma unroll
                for (int i = 0; i < 4; i++) {
                    const float p = exp2f(s[qi][mt][i] - mnew);
                    s[qi][mt][i] = p;
                    sum += p;
                }
            sum += __shfl_xor(sum, 16);
            sum += __shfl_xor(sum, 32);
            lrun[qi] = lrun[qi] * alpha + sum;
            mrun[qi] = mnew;
#pragma unroll
            for (int nt = 0; nt < 4; nt++) yacc[qi][nt] *= alpha;

            // P^T rows=query: Pl[wave][qi*16+l15][key]
#pragma unroll
            for (int mt = 0; mt < 4; mt++)
#pragma unroll
                for (int i = 0; i < 4; i++)
                    Pl[wave][qi * 16 + l15][mt * 16 + quad * 4 + i] = (bf16)s[qi][mt][i];
        }

        // ---- V fragments (A-operand [m=hd][k=key]) ----
        bf16x8 vf[4][2];
#pragma unroll
        for (int nt = 0; nt < 4; nt++) {
            vf[nt][0] = *(const bf16x8*)&Vl[nt * 16 + l15][quad * 8];
            vf[nt][1] = *(const bf16x8*)&Vl[nt * 16 + l15][32 + quad * 8];
        }

        // ---- PV: O^T += V^T P^T (P as B-operand [n=query][k=key]) ----
#pragma unroll
        for (int qi = 0; qi < 2; qi++)
#pragma unroll
            for (int ks = 0; ks < 2; ks++) {
                const bf16x8 pf = *(const bf16x8*)&Pl[wave][qi * 16 + l15][ks * 32 + quad * 8];
#pragma unroll
                for (int nt = 0; nt < 4; nt++)
                    yacc[qi][nt] = __builtin_amdgcn_mfma_f32_16x16x32_bf16(
                        vf[nt][ks], pf, yacc[qi][nt], 0, 0, 0);
            }
    }

    // ---- normalize, store Y[b][s][h*64+hd] (O^T: lane=query, regs=hd) ----
#pragma unroll
    for (int qi = 0; qi < 2; qi++) {
        const float inv = 1.0f / lrun[qi];
        bf16* yp = Y + (rowbase + q0 + wave * 32 + qi * 16 + l15) * (size_t)Dc + h * 64;
#pragma unroll
        for (int nt = 0; nt < 4; nt++)
#pragma unroll
            for (int i = 0; i < 4; i++)
                yp[nt * 16 + quad * 4 + i] = (bf16)(yacc[qi][nt][i] * inv);
    }
}

// ---------------------------------------------------------------------------
extern "C" void kernel_launch(void* const* d_in, const int* in_sizes, int n_in,
                              void* d_out, int out_size, void* d_ws, size_t ws_size,
                              hipStream_t stream) {
    const float* q  = (const float*)d_in[0];
    const float* k  = (const float*)d_in[1];
    const float* v  = (const float*)d_in[2];
    const float* Wq = (const float*)d_in[3];
    const float* bq = (const float*)d_in[4];
    const float* Wk = (const float*)d_in[5];
    const float* bk = (const float*)d_in[6];
    const float* Wv = (const float*)d_in[7];
    const float* bv = (const float*)d_in[8];
    const float* Wo = (const float*)d_in[9];
    const float* bo = (const float*)d_in[10];
    float* out = (float*)d_out;

    const int M = Bc * Sc;   // 8192
    const int N = Dc;        // 1024
    const int K = Dc;        // 1024
    const size_t E  = (size_t)Bc * Sc * Dc;  // 8388608
    const size_t EW = (size_t)Dc * Dc;       // 1048576

    // d_out: Qh | Kh (bf16; dead before final GEMM writes fp32).
    // d_ws:  tmpA | VtG | Wqb|Wkb|Wvb|Wob  (41.9 MB; <= 50.3 MB proven in r2).
    bf16* Qh   = (bf16*)d_out;
    bf16* Kh   = Qh + E;
    bf16* tmpA = (bf16*)d_ws;
    bf16* VtG  = tmpA + E;
    bf16* Wqb  = VtG + E;
    bf16* Wkb  = Wqb + EW;
    bf16* Wvb  = Wkb + EW;
    bf16* Wob  = Wvb + EW;

    const int n16  = (int)(E / 16);          // 524288
    const int n16w = (int)(EW / 16);         // 65536
    dim3 gc(n16 / 256);                      // 2048
    dim3 gw(n16w / 256);                     // 256
    dim3 gg(M / BM, N / BN);                 // 64 x 8
    dim3 ga(Sc / 128, Bc * Hc);              // 16 x 64

    cvt_f32_bf16<<<gw, 256, 0, stream>>>(Wq, Wqb, n16w);
    cvt_f32_bf16<<<gw, 256, 0, stream>>>(Wk, Wkb, n16w);
    cvt_f32_bf16<<<gw, 256, 0, stream>>>(Wv, Wvb, n16w);
    cvt_f32_bf16<<<gw, 256, 0, stream>>>(Wo, Wob, n16w);

    cvt_f32_bf16<<<gc, 256, 0, stream>>>(q, tmpA, n16);
    gemm_bb<bf16, false><<<gg, 256, 0, stream>>>(tmpA, Wqb, bq, Qh, M, N, K);

    cvt_f32_bf16<<<gc, 256, 0, stream>>>(k, tmpA, n16);
    gemm_bb<bf16, false><<<gg, 256, 0, stream>>>(tmpA, Wkb, bk, Kh, M, N, K);

    cvt_f32_bf16<<<gc, 256, 0, stream>>>(v, tmpA, n16);
    gemm_bb<bf16, true><<<gg, 256, 0, stream>>>(tmpA, Wvb, bv, VtG, M, N, K);

    attn_flash<<<ga, 256, 0, stream>>>(Qh, Kh, VtG, tmpA);

    gemm_bb<float, false><<<gg, 256, 0, stream>>>(tmpA, Wob, bo, out, M, N, K);
}

// Round 6
// 389.657 us; speedup vs baseline: 1.7825x; 1.1339x over previous
//
#include <hip/hip_runtime.h>
#include <hip/hip_bf16.h>
#include <cstdint>
#include <cstddef>

// Problem constants (B,S,D,H fixed by the reference)
#define Bc 4
#define Sc 2048
#define Dc 1024
#define Hc 16
// HD = 64

typedef __bf16 bf16;
typedef bf16  bf16x4 __attribute__((ext_vector_type(4)));
typedef bf16  bf16x8 __attribute__((ext_vector_type(8)));
typedef float f32x4  __attribute__((ext_vector_type(4)));

__device__ __forceinline__ void load_lds16(const bf16* g, bf16* l) {
    __builtin_amdgcn_global_load_lds((const __attribute__((address_space(1))) void*)g,
                                     (__attribute__((address_space(3))) void*)l,
                                     16, 0, 0);
}

// 16 fp32 -> two bf16x8
__device__ __forceinline__ void cvt16(const float* __restrict__ g,
                                      bf16x8& lo, bf16x8& hi) {
    const f32x4 a0 = *(const f32x4*)(g);
    const f32x4 a1 = *(const f32x4*)(g + 4);
    const f32x4 a2 = *(const f32x4*)(g + 8);
    const f32x4 a3 = *(const f32x4*)(g + 12);
#pragma unroll
    for (int j = 0; j < 4; j++) {
        lo[j]     = (bf16)a0[j];
        lo[j + 4] = (bf16)a1[j];
        hi[j]     = (bf16)a2[j];
        hi[j + 4] = (bf16)a3[j];
    }
}

__device__ __forceinline__ void store_relu(float* p, float v) { *p = fmaxf(v, 0.0f); }
__device__ __forceinline__ void store_relu(bf16*  p, float v) { *p = (bf16)fmaxf(v, 0.0f); }

// ---------------------------------------------------------------------------
// fp32 -> bf16 conversion (16 elems/thread)
// ---------------------------------------------------------------------------
__global__ __launch_bounds__(256)
void cvt_f32_bf16(const float* __restrict__ src, bf16* __restrict__ dst, int n16) {
    const int idx = blockIdx.x * 256 + threadIdx.x;
    if (idx >= n16) return;
    bf16x8 lo, hi;
    cvt16(src + (size_t)idx * 16, lo, hi);
    *(bf16x8*)(dst + (size_t)idx * 16)     = lo;
    *(bf16x8*)(dst + (size_t)idx * 16 + 8) = hi;
}

// ---------------------------------------------------------------------------
// GEMM: C = relu(A[M,K] @ W[N,K]^T + bias), bf16 in, fp32 accum.
// 128x128 tile, BK=64 (16 k-iters), global_load_lds width-16 staging.
// LDS uses XOR swizzle: logical (row,col) stored at row*64 + (col ^ ((row&7)*8))
// -> all ds_read_b128 fragment reads are 2-way (free) instead of 8-16-way.
// TR=true: V-projection epilogue writes per-head transposed Vt_g[b][h][hd][s],
// reusing the main LDS pool for the transpose buffer.
// ---------------------------------------------------------------------------
#define BM 128
#define BN 128
#define BK 64

template <typename TC, bool TR>
__global__ __launch_bounds__(256)
void gemm_bb(const bf16* __restrict__ A, const bf16* __restrict__ W,
             const float* __restrict__ bias, TC* __restrict__ C,
             int M, int N, int K) {
    constexpr int POOL = TR ? 36864 : 32768;      // bytes
    __shared__ __align__(16) char pool[POOL];
    bf16* lA = (bf16*)pool;                        // [BM*BK] = 16 KB
    bf16* lB = (bf16*)(pool + 16384);              // [BN*BK] = 16 KB

    const int t    = threadIdx.x;
    const int lane = t & 63;
    const int wave = t >> 6;
    const int l15  = lane & 15;
    const int quad = lane >> 4;

    const int m0 = blockIdx.x * BM;
    const int n0 = blockIdx.y * BN;
    const int wm = (wave >> 1) * 64;
    const int wn = (wave & 1) * 64;

    f32x4 acc[4][4] = {};

    // staging map: thread t, chunk c: flat slot f = t*8 + c*2048
    //   row = f>>6 = (t>>3) + 32c ; stored col = (t&7)*8 ;
    //   logical col cg = stored ^ ((row&7)*8), row&7 == (t>>3)&7 for all c.
    const int srow = t >> 3;                          // 0..31
    const int cg   = (((t & 7) ^ (srow & 7)) << 3);   // swizzled logical col
    const bf16* gA = A + (size_t)(m0 + srow) * K + cg;
    const bf16* gW = W + (size_t)(n0 + srow) * K + cg;
    bf16* lA0 = lA + t * 8;
    bf16* lB0 = lB + t * 8;

    for (int k0 = 0; k0 < K; k0 += BK) {
        __syncthreads();               // previous tiles fully consumed
#pragma unroll
        for (int c = 0; c < 4; c++) {
            load_lds16(gA + (size_t)(32 * c) * K, lA0 + c * 2048);
            load_lds16(gW + (size_t)(32 * c) * K, lB0 + c * 2048);
        }
        gA += BK; gW += BK;
        __syncthreads();               // drains vmcnt -> tiles published

#pragma unroll
        for (int ks = 0; ks < 2; ks++) {
            bf16x8 af[4], bfr[4];
#pragma unroll
            for (int mt = 0; mt < 4; mt++) {
                const int row = wm + mt * 16 + l15;
                const int colp = ((((ks << 2) | quad) ^ (l15 & 7)) << 3);
                af[mt] = *(const bf16x8*)(lA + row * BK + colp);
            }
#pragma unroll
            for (int nt = 0; nt < 4; nt++) {
                const int row = wn + nt * 16 + l15;
                const int colp = ((((ks << 2) | quad) ^ (l15 & 7)) << 3);
                bfr[nt] = *(const bf16x8*)(lB + row * BK + colp);
            }
#pragma unroll
            for (int mt = 0; mt < 4; mt++)
#pragma unroll
                for (int nt = 0; nt < 4; nt++)
                    acc[mt][nt] = __builtin_amdgcn_mfma_f32_16x16x32_bf16(
                        af[mt], bfr[nt], acc[mt][nt], 0, 0, 0);
        }
    }

    if constexpr (!TR) {
        // C/D layout: col = lane&15, row = quad*4 + i
#pragma unroll
        for (int nt = 0; nt < 4; nt++) {
            const int col = n0 + wn + nt * 16 + l15;
            const float bv = bias[col];
#pragma unroll
            for (int mt = 0; mt < 4; mt++) {
                const int rowb = m0 + wm + mt * 16 + quad * 4;
#pragma unroll
                for (int i = 0; i < 4; i++)
                    store_relu(&C[(size_t)(rowb + i) * N + col], acc[mt][nt][i] + bv);
            }
        }
    } else {
        // Transposed per-head output. Reuse pool as tr[4][64][72] (36864 B).
        __syncthreads();               // everyone done reading lA/lB
        bf16* trp = (bf16*)pool;       // tr[w][r][c] = trp[(w*64+r)*72 + c]
#pragma unroll
        for (int nt = 0; nt < 4; nt++) {
            const int col = n0 + wn + nt * 16 + l15;
            const float bv = bias[col];
#pragma unroll
            for (int mt = 0; mt < 4; mt++)
#pragma unroll
                for (int i = 0; i < 4; i++)
                    trp[((wave * 64) + nt * 16 + l15) * 72 + mt * 16 + quad * 4 + i] =
                        (bf16)fmaxf(acc[mt][nt][i] + bv, 0.0f);
        }
        __syncthreads();
        const int r2 = lane >> 3;          // 0..7
        const int c8 = (lane & 7) * 8;     // 0..56
#pragma unroll
        for (int rr = 0; rr < 8; rr++) {
            const int rt = rr * 8 + r2;                  // quadrant col (hd dim)
            const bf16x8 vv = *(const bf16x8*)&trp[((wave * 64) + rt) * 72 + c8];
            const int cg2 = n0 + wn + rt;                // global col
            const int h   = cg2 >> 6, hd = cg2 & 63;
            const int mg  = m0 + wm + c8;                // global row base
            const int b   = mg >> 11, s = mg & (Sc - 1);
            bf16* dst = (bf16*)C + ((size_t)(b * Hc + h) * 64 + hd) * Sc + s;
            *(bf16x8*)dst = vv;
        }
    }
}

// ---------------------------------------------------------------------------
// Flash attention, transposed-score form, FIXED-MAX softmax.
// Q,K are post-ReLU => all scores >= 0 and bounded (~<=6 in exp2 domain;
// fp32 exp2 overflows at 128 — enormous margin), so p = exp2(s) with no
// running max, no alpha rescale; normalization sum deferred to the end.
// 128 queries/block (4 waves x 2 Q-frags), 64-key tiles.
// V pre-transposed per head: Vt_g[b][h][hd][s]. O accumulated transposed.
// ---------------------------------------------------------------------------
__global__ __launch_bounds__(256)
void attn_flash(const bf16* __restrict__ Qh, const bf16* __restrict__ Kh,
                const bf16* __restrict__ Vt_g, bf16* __restrict__ Y) {
    __shared__ __align__(16) bf16 Kl[64][72];      // [key][hd]
    __shared__ __align__(16) bf16 Vl[64][72];      // [hd][key]
    __shared__ __align__(16) bf16 Pl[4][32][72];   // per-wave P^T rows=query

    const int t    = threadIdx.x;
    const int lane = t & 63;
    const int wave = t >> 6;
    const int l15  = lane & 15;
    const int quad = lane >> 4;

    const int qt = blockIdx.x;          // 0..15
    const int bh = blockIdx.y;          // 0..63
    const int b  = bh >> 4;
    const int h  = bh & 15;
    const int q0 = qt * 128;
    const size_t rowbase = (size_t)b * Sc;
    const size_t vhead   = (size_t)(b * Hc + h) * 64;

    // Q fragments as B-operand [n=query=l15][k=hd=quad*8+j], prescaled by
    // 1/8 * log2(e) so scores land in the exp2 domain.
    const float qscale = 0.125f * 1.44269504f;
    bf16x8 qf[2][2];
#pragma unroll
    for (int qi = 0; qi < 2; qi++) {
        const bf16* qp = Qh + (rowbase + q0 + wave * 32 + qi * 16 + l15) * (size_t)Dc + h * 64;
#pragma unroll
        for (int ks = 0; ks < 2; ks++) {
            const bf16x8 raw = *(const bf16x8*)(qp + ks * 32 + quad * 8);
#pragma unroll
            for (int j = 0; j < 8; j++) qf[qi][ks][j] = (bf16)((float)raw[j] * qscale);
        }
    }

    float lrun[2] = {0.0f, 0.0f};       // in-lane partial sums (this quad's keys)
    f32x4 yacc[2][4] = {};              // O^T: col=query=l15, row=hd

    // staging map: thread covers row sr, cols [sc, sc+16)
    const int sr = t >> 2;
    const int sc = (t & 3) * 16;

    for (int kt = 0; kt < Sc / 64; kt++) {
        const int kb = kt * 64;
        const bf16* kp = Kh + (rowbase + kb + sr) * (size_t)Dc + h * 64 + sc;
        const bf16* vp = Vt_g + (vhead + sr) * (size_t)Sc + kb + sc;
        const bf16x8 k0 = *(const bf16x8*)kp;
        const bf16x8 k1 = *(const bf16x8*)(kp + 8);
        const bf16x8 v0 = *(const bf16x8*)vp;
        const bf16x8 v1 = *(const bf16x8*)(vp + 8);
        __syncthreads();                // prev tile fully consumed
        *(bf16x8*)&Kl[sr][sc]     = k0;
        *(bf16x8*)&Kl[sr][sc + 8] = k1;
        *(bf16x8*)&Vl[sr][sc]     = v0;
        *(bf16x8*)&Vl[sr][sc + 8] = v1;
        __syncthreads();                // tiles published

        // ---- K fragments (A-operand [m=key][k=hd]), shared across qi ----
        bf16x8 kf[4][2];
#pragma unroll
        for (int mt = 0; mt < 4; mt++) {
            kf[mt][0] = *(const bf16x8*)&Kl[mt * 16 + l15][quad * 8];
            kf[mt][1] = *(const bf16x8*)&Kl[mt * 16 + l15][32 + quad * 8];
        }

        // ---- scores S^T: col=query=l15, row=key=mt*16+quad*4+i ----
        f32x4 s[2][4];
#pragma unroll
        for (int qi = 0; qi < 2; qi++)
#pragma unroll
            for (int mt = 0; mt < 4; mt++) {
                s[qi][mt] = (f32x4){0.f, 0.f, 0.f, 0.f};
                s[qi][mt] = __builtin_amdgcn_mfma_f32_16x16x32_bf16(
                    kf[mt][0], qf[qi][0], s[qi][mt], 0, 0, 0);
                s[qi][mt] = __builtin_amdgcn_mfma_f32_16x16x32_bf16(
                    kf[mt][1], qf[qi][1], s[qi][mt], 0, 0, 0);
            }

        // ---- fixed-max softmax: p = exp2(s); in-lane partial sum only ----
#pragma unroll
        for (int qi = 0; qi < 2; qi++) {
            float sum = 0.f;
#pragma unroll
            for (int mt = 0; mt < 4; mt++) {
#pragma unroll
                for (int i = 0; i < 4; i++) {
                    const float p = exp2f(s[qi][mt][i]);
                    s[qi][mt][i] = p;
                    sum += p;
                }
                bf16x4 pk;
#pragma unroll
                for (int i = 0; i < 4; i++) pk[i] = (bf16)s[qi][mt][i];
                *(bf16x4*)&Pl[wave][qi * 16 + l15][mt * 16 + quad * 4] = pk;
            }
            lrun[qi] += sum;
        }

        // ---- V fragments (A-operand [m=hd][k=key]) ----
        bf16x8 vf[4][2];
#pragma unroll
        for (int nt = 0; nt < 4; nt++) {
            vf[nt][0] = *(const bf16x8*)&Vl[nt * 16 + l15][quad * 8];
            vf[nt][1] = *(const bf16x8*)&Vl[nt * 16 + l15][32 + quad * 8];
        }

        // ---- PV: O^T += V^T P^T (P as B-operand [n=query][k=key]) ----
#pragma unroll
        for (int qi = 0; qi < 2; qi++)
#pragma unroll
            for (int ks = 0; ks < 2; ks++) {
                const bf16x8 pf = *(const bf16x8*)&Pl[wave][qi * 16 + l15][ks * 32 + quad * 8];
#pragma unroll
                for (int nt = 0; nt < 4; nt++)
                    yacc[qi][nt] = __builtin_amdgcn_mfma_f32_16x16x32_bf16(
                        vf[nt][ks], pf, yacc[qi][nt], 0, 0, 0);
            }
    }

    // ---- cross-quad sum reduction (once), normalize, store ----
#pragma unroll
    for (int qi = 0; qi < 2; qi++) {
        float l = lrun[qi];
        l += __shfl_xor(l, 16);
        l += __shfl_xor(l, 32);
        const float inv = 1.0f / l;
        bf16* yp = Y + (rowbase + q0 + wave * 32 + qi * 16 + l15) * (size_t)Dc + h * 64;
#pragma unroll
        for (int nt = 0; nt < 4; nt++)
#pragma unroll
            for (int i = 0; i < 4; i++)
                yp[nt * 16 + quad * 4 + i] = (bf16)(yacc[qi][nt][i] * inv);
    }
}

// ---------------------------------------------------------------------------
extern "C" void kernel_launch(void* const* d_in, const int* in_sizes, int n_in,
                              void* d_out, int out_size, void* d_ws, size_t ws_size,
                              hipStream_t stream) {
    const float* q  = (const float*)d_in[0];
    const float* k  = (const float*)d_in[1];
    const float* v  = (const float*)d_in[2];
    const float* Wq = (const float*)d_in[3];
    const float* bq = (const float*)d_in[4];
    const float* Wk = (const float*)d_in[5];
    const float* bk = (const float*)d_in[6];
    const float* Wv = (const float*)d_in[7];
    const float* bv = (const float*)d_in[8];
    const float* Wo = (const float*)d_in[9];
    const float* bo = (const float*)d_in[10];
    float* out = (float*)d_out;

    const int M = Bc * Sc;   // 8192
    const int N = Dc;        // 1024
    const int K = Dc;        // 1024
    const size_t E  = (size_t)Bc * Sc * Dc;  // 8388608
    const size_t EW = (size_t)Dc * Dc;       // 1048576

    // d_out: Qh | Kh (bf16; dead before final GEMM writes fp32).
    // d_ws:  tmpA | VtG | Wqb|Wkb|Wvb|Wob  (41.9 MB; proven in r5).
    bf16* Qh   = (bf16*)d_out;
    bf16* Kh   = Qh + E;
    bf16* tmpA = (bf16*)d_ws;
    bf16* VtG  = tmpA + E;
    bf16* Wqb  = VtG + E;
    bf16* Wkb  = Wqb + EW;
    bf16* Wvb  = Wkb + EW;
    bf16* Wob  = Wvb + EW;

    const int n16  = (int)(E / 16);          // 524288
    const int n16w = (int)(EW / 16);         // 65536
    dim3 gc(n16 / 256);                      // 2048
    dim3 gw(n16w / 256);                     // 256
    dim3 gg(M / BM, N / BN);                 // 64 x 8
    dim3 ga(Sc / 128, Bc * Hc);              // 16 x 64

    cvt_f32_bf16<<<gw, 256, 0, stream>>>(Wq, Wqb, n16w);
    cvt_f32_bf16<<<gw, 256, 0, stream>>>(Wk, Wkb, n16w);
    cvt_f32_bf16<<<gw, 256, 0, stream>>>(Wv, Wvb, n16w);
    cvt_f32_bf16<<<gw, 256, 0, stream>>>(Wo, Wob, n16w);

    cvt_f32_bf16<<<gc, 256, 0, stream>>>(q, tmpA, n16);
    gemm_bb<bf16, false><<<gg, 256, 0, stream>>>(tmpA, Wqb, bq, Qh, M, N, K);

    cvt_f32_bf16<<<gc, 256, 0, stream>>>(k, tmpA, n16);
    gemm_bb<bf16, false><<<gg, 256, 0, stream>>>(tmpA, Wkb, bk, Kh, M, N, K);

    cvt_f32_bf16<<<gc, 256, 0, stream>>>(v, tmpA, n16);
    gemm_bb<bf16, true><<<gg, 256, 0, stream>>>(tmpA, Wvb, bv, VtG, M, N, K);

    attn_flash<<<ga, 256, 0, stream>>>(Qh, Kh, VtG, tmpA);

    gemm_bb<float, false><<<gg, 256, 0, stream>>>(tmpA, Wob, bo, out, M, N, K);
}